// Round 6
// baseline (288.309 us; speedup 1.0000x reference)
//
#include <hip/hip_runtime.h>

// Trilinear resize [4,128,128,128,2] f32 -> [4,192,192,192,2] f32.
// zoom = 1.5 exactly => per axis, weights periodic with period
// 3 outputs / 2 inputs: output o = 3m+r: i0 = 2m + (r==2);
// w0 = {1, 1/3, 2/3}[r]; w1 = 1-w0.
//
// v6: A/B of the store path ONLY vs v5 — nontemporal hint removed
// (plain global_store_dwordx4). Rationale: kernel is HBM-BW-bound
// (queueing, not latency: 4 waves/SIMD x 12 in-flight loads oversubscribe
// HBM ~50x, so stalls are bandwidth-queueing and occupancy is moot);
// stores are 70% of traffic and the NT hint is the only never-tested
// component. Harness's own fillBufferAligned proves plain dwordx4
// stores sustain 6.5 TB/s. All else identical to v5: block-private
// input bricks (x-pair x y-triple x 2-z-triple march), aligned 16B quad
// loads, register-carried shared plane, launch_bounds(192,4).

#define IN_D  128
#define OUT_D 192
#define OUT_XP 96
#define YT_PER_BLOCK 2   // y-triples per block (block covers 6 output y)
#define ZT_PER_CHUNK 2   // z-triples marched per thread (6 output z)
#define NZC 32           // 64 z-triples / ZT_PER_CHUNK
#define ROW_Q 64         // input row length in float4 units

__device__ __forceinline__ float4 f4lerp(float4 a, float4 b, float wa, float wb) {
    float4 r;
    r.x = a.x * wa + b.x * wb;
    r.y = a.y * wa + b.y * wb;
    r.z = a.z * wa + b.z * wb;
    r.w = a.w * wa + b.w * wb;
    return r;
}

__global__ __launch_bounds__(192, 4) void resize_trilinear_kernel(
        const float4* __restrict__ in4, float4* __restrict__ out) {
    const int xp = (int)threadIdx.x;                               // 0..95
    const int yt = (int)(blockIdx.x * YT_PER_BLOCK + threadIdx.y); // 0..63
    const int zc = (int)blockIdx.y;                                // 0..31
    const int b  = (int)blockIdx.z;                                // 0..3

    const float THIRD = 0.33333334f;
    const float TWO3  = 0.66666669f;

    // ---- x pair (outputs x = 2*xp, 2*xp+1) ----
    unsigned xo = 2u * (unsigned)xp;
    unsigned mx = xo / 3u;               // magic-mul
    unsigned rx = xo - 3u * mx;
    const int q0o = (int)mx;
    const bool clip = (mx == 63u);       // xp==95: clamp second quad into row
    const int q1o = clip ? 63 : (int)mx + 1;
    float wxa0 = (rx == 0u) ? 1.0f : ((rx == 1u) ? THIRD : TWO3);
    float wxa1 = 1.0f - wxa0;
    float wxb0 = (rx == 0u) ? THIRD : ((rx == 1u) ? TWO3 : 1.0f);
    float wxb1 = 1.0f - wxb0;

    // ---- y triple (outputs y = 3*yt .. 3*yt+2 from rows 2yt..2yt+2) ----
    const int yr0 = 2 * yt;
    const int yr1 = yr0 + 1;
    const int yr2 = min(yr0 + 2, IN_D - 1);

    const float4* basep = in4 + (size_t)b * (IN_D * IN_D * ROW_Q);

    auto plane_load = [&](int pz, float4 q[6]) {
        const float4* p  = basep + (size_t)pz * (IN_D * ROW_Q);
        const float4* r0 = p + (size_t)yr0 * ROW_Q;
        const float4* r1 = p + (size_t)yr1 * ROW_Q;
        const float4* r2 = p + (size_t)yr2 * ROW_Q;
        q[0] = r0[q0o]; q[1] = r0[q1o];
        q[2] = r1[q0o]; q[3] = r1[q1o];
        q[4] = r2[q0o]; q[5] = r2[q1o];
    };

    auto rowx = [&](float4 qa, float4 qb) -> float4 {
        float2 e0 = make_float2(qa.x, qa.y);
        float2 e1 = make_float2(qa.z, qa.w);
        float2 e2 = clip ? make_float2(qb.z, qb.w) : make_float2(qb.x, qb.y);
        float2 e3 = make_float2(qb.z, qb.w);
        float2 f0 = (rx == 2u) ? e1 : e0;
        float2 f1 = (rx == 2u) ? e2 : e1;
        float2 g0 = (rx == 0u) ? e0 : ((rx == 1u) ? e1 : e2);
        float2 g1 = (rx == 0u) ? e1 : ((rx == 1u) ? e2 : e3);
        float4 X;
        X.x = f0.x * wxa0 + f1.x * wxa1;
        X.y = f0.y * wxa0 + f1.y * wxa1;
        X.z = g0.x * wxb0 + g1.x * wxb1;
        X.w = g0.y * wxb0 + g1.y * wxb1;
        return X;
    };

    auto plane_comp = [&](const float4 q[6], float4 U[3]) {
        float4 X0 = rowx(q[0], q[1]);
        float4 X1 = rowx(q[2], q[3]);
        float4 X2 = rowx(q[4], q[5]);
        U[0] = X0;                            // out y=3yt
        U[1] = f4lerp(X0, X1, THIRD, TWO3);   // out y=3yt+1
        U[2] = f4lerp(X1, X2, TWO3, THIRD);   // out y=3yt+2
    };

    // ---- z march: 2 triples, carrying shared plane in regs ----
    const int zt0 = zc * ZT_PER_CHUNK;
    float4 qA[6], UA[3];
    plane_load(2 * zt0, qA);
    plane_comp(qA, UA);

    const size_t zs = (size_t)OUT_D * OUT_XP; // one output z-plane
    size_t ob = (((size_t)b * OUT_D + 3 * zt0) * OUT_D + 3 * yt) * OUT_XP + xp;

#pragma unroll
    for (int t = 0; t < ZT_PER_CHUNK; ++t) {
        const int zt = zt0 + t;
        float4 qB[6], qC[6];
        plane_load(2 * zt + 1, qB);                 // all 12 loads issue
        plane_load(min(2 * zt + 2, IN_D - 1), qC);  // before any compute
        float4 UB[3], UC[3];
        plane_comp(qB, UB);
        plane_comp(qC, UC);

#pragma unroll
        for (int yi = 0; yi < 3; ++yi) {
            float4 o0 = UA[yi];                               // z=3zt
            float4 o1 = f4lerp(UA[yi], UB[yi], THIRD, TWO3);  // z=3zt+1
            float4 o2 = f4lerp(UB[yi], UC[yi], TWO3, THIRD);  // z=3zt+2
            size_t oy = ob + (size_t)yi * OUT_XP;
            out[oy]          = o0;    // plain stores (A/B vs v5's NT)
            out[oy + zs]     = o1;
            out[oy + 2 * zs] = o2;
        }
        ob += 3 * zs;
        UA[0] = UC[0]; UA[1] = UC[1]; UA[2] = UC[2];  // carry plane 2(zt+1)
    }
}

extern "C" void kernel_launch(void* const* d_in, const int* in_sizes, int n_in,
                              void* d_out, int out_size, void* d_ws, size_t ws_size,
                              hipStream_t stream) {
    const float4* in4 = (const float4*)d_in[0];
    float4* out = (float4*)d_out;

    dim3 block(OUT_XP, YT_PER_BLOCK, 1);   // 192 threads = 3 waves
    dim3 grid(64 / YT_PER_BLOCK, NZC, 4);  // 32 x 32 x 4 = 4096 blocks
    resize_trilinear_kernel<<<grid, block, 0, stream>>>(in4, out);
}

// Round 7
// 275.278 us; speedup vs baseline: 1.0473x; 1.0473x over previous
//
#include <hip/hip_runtime.h>

// Trilinear resize [4,128,128,128,2] f32 -> [4,192,192,192,2] f32.
// zoom = 1.5 exactly => per axis, weights periodic with period
// 3 outputs / 2 inputs: output o = 3m+r: i0 = 2m + (r==2);
// w0 = {1, 1/3, 2/3}[r]; w1 = 1-w0.
//
// v7 == v5 restored (best measured config). The v5-vs-v6 A/B showed
// nontemporal stores beat plain stores by ~5-12 us (NT keeps the 226 MB
// write stream from evicting block-shared input rows out of L2).
// Structure: block-private input bricks (x-pair x y-triple x 2-z-triple
// march per thread), aligned 16B quad loads (2/row), register-carried
// shared z-plane, launch_bounds(192,4) => 16 waves/CU, 4096 blocks.
// Measured ladder: 304.7 (v2) -> 284.6 (v3 block-private) -> 278.5
// (v4 aligned reads) -> 275.6 (v5 occupancy+NT) -> 288.3 (v6 plain
// stores, regression) -> v7 = v5.
// Floor arithmetic: 226 MB writes + 120 MB reads ~= 55 us at 6.3 TB/s;
// remaining dur_us is dominated by harness poison-fills (~140 us each,
// all top-5 dispatches, themselves at 80% HBM peak).

#define IN_D  128
#define OUT_D 192
#define OUT_XP 96
#define YT_PER_BLOCK 2   // y-triples per block (block covers 6 output y)
#define ZT_PER_CHUNK 2   // z-triples marched per thread (6 output z)
#define NZC 32           // 64 z-triples / ZT_PER_CHUNK
#define ROW_Q 64         // input row length in float4 units

typedef float nfloat4 __attribute__((ext_vector_type(4)));

__device__ __forceinline__ float4 f4lerp(float4 a, float4 b, float wa, float wb) {
    float4 r;
    r.x = a.x * wa + b.x * wb;
    r.y = a.y * wa + b.y * wb;
    r.z = a.z * wa + b.z * wb;
    r.w = a.w * wa + b.w * wb;
    return r;
}

__global__ __launch_bounds__(192, 4) void resize_trilinear_kernel(
        const float4* __restrict__ in4, float4* __restrict__ out) {
    const int xp = (int)threadIdx.x;                               // 0..95
    const int yt = (int)(blockIdx.x * YT_PER_BLOCK + threadIdx.y); // 0..63
    const int zc = (int)blockIdx.y;                                // 0..31
    const int b  = (int)blockIdx.z;                                // 0..3

    const float THIRD = 0.33333334f;
    const float TWO3  = 0.66666669f;

    // ---- x pair (outputs x = 2*xp, 2*xp+1) ----
    unsigned xo = 2u * (unsigned)xp;
    unsigned mx = xo / 3u;               // magic-mul
    unsigned rx = xo - 3u * mx;
    const int q0o = (int)mx;
    const bool clip = (mx == 63u);       // xp==95: clamp second quad into row
    const int q1o = clip ? 63 : (int)mx + 1;
    float wxa0 = (rx == 0u) ? 1.0f : ((rx == 1u) ? THIRD : TWO3);
    float wxa1 = 1.0f - wxa0;
    float wxb0 = (rx == 0u) ? THIRD : ((rx == 1u) ? TWO3 : 1.0f);
    float wxb1 = 1.0f - wxb0;

    // ---- y triple (outputs y = 3*yt .. 3*yt+2 from rows 2yt..2yt+2) ----
    const int yr0 = 2 * yt;
    const int yr1 = yr0 + 1;
    const int yr2 = min(yr0 + 2, IN_D - 1);

    const float4* basep = in4 + (size_t)b * (IN_D * IN_D * ROW_Q);

    auto plane_load = [&](int pz, float4 q[6]) {
        const float4* p  = basep + (size_t)pz * (IN_D * ROW_Q);
        const float4* r0 = p + (size_t)yr0 * ROW_Q;
        const float4* r1 = p + (size_t)yr1 * ROW_Q;
        const float4* r2 = p + (size_t)yr2 * ROW_Q;
        q[0] = r0[q0o]; q[1] = r0[q1o];
        q[2] = r1[q0o]; q[3] = r1[q1o];
        q[4] = r2[q0o]; q[5] = r2[q1o];
    };

    auto rowx = [&](float4 qa, float4 qb) -> float4 {
        float2 e0 = make_float2(qa.x, qa.y);
        float2 e1 = make_float2(qa.z, qa.w);
        float2 e2 = clip ? make_float2(qb.z, qb.w) : make_float2(qb.x, qb.y);
        float2 e3 = make_float2(qb.z, qb.w);
        float2 f0 = (rx == 2u) ? e1 : e0;
        float2 f1 = (rx == 2u) ? e2 : e1;
        float2 g0 = (rx == 0u) ? e0 : ((rx == 1u) ? e1 : e2);
        float2 g1 = (rx == 0u) ? e1 : ((rx == 1u) ? e2 : e3);
        float4 X;
        X.x = f0.x * wxa0 + f1.x * wxa1;
        X.y = f0.y * wxa0 + f1.y * wxa1;
        X.z = g0.x * wxb0 + g1.x * wxb1;
        X.w = g0.y * wxb0 + g1.y * wxb1;
        return X;
    };

    auto plane_comp = [&](const float4 q[6], float4 U[3]) {
        float4 X0 = rowx(q[0], q[1]);
        float4 X1 = rowx(q[2], q[3]);
        float4 X2 = rowx(q[4], q[5]);
        U[0] = X0;                            // out y=3yt
        U[1] = f4lerp(X0, X1, THIRD, TWO3);   // out y=3yt+1
        U[2] = f4lerp(X1, X2, TWO3, THIRD);   // out y=3yt+2
    };

    auto nt_store = [&](size_t idx, float4 v) {
        nfloat4 nv;
        nv.x = v.x; nv.y = v.y; nv.z = v.z; nv.w = v.w;
        __builtin_nontemporal_store(nv, (nfloat4*)&out[idx]);
    };

    // ---- z march: 2 triples, carrying shared plane in regs ----
    const int zt0 = zc * ZT_PER_CHUNK;
    float4 qA[6], UA[3];
    plane_load(2 * zt0, qA);
    plane_comp(qA, UA);

    const size_t zs = (size_t)OUT_D * OUT_XP; // one output z-plane
    size_t ob = (((size_t)b * OUT_D + 3 * zt0) * OUT_D + 3 * yt) * OUT_XP + xp;

#pragma unroll
    for (int t = 0; t < ZT_PER_CHUNK; ++t) {
        const int zt = zt0 + t;
        float4 qB[6], qC[6];
        plane_load(2 * zt + 1, qB);                 // all 12 loads issue
        plane_load(min(2 * zt + 2, IN_D - 1), qC);  // before any compute
        float4 UB[3], UC[3];
        plane_comp(qB, UB);
        plane_comp(qC, UC);

#pragma unroll
        for (int yi = 0; yi < 3; ++yi) {
            float4 o0 = UA[yi];                               // z=3zt
            float4 o1 = f4lerp(UA[yi], UB[yi], THIRD, TWO3);  // z=3zt+1
            float4 o2 = f4lerp(UB[yi], UC[yi], TWO3, THIRD);  // z=3zt+2
            size_t oy = ob + (size_t)yi * OUT_XP;
            nt_store(oy,          o0);
            nt_store(oy + zs,     o1);
            nt_store(oy + 2 * zs, o2);
        }
        ob += 3 * zs;
        UA[0] = UC[0]; UA[1] = UC[1]; UA[2] = UC[2];  // carry plane 2(zt+1)
    }
}

extern "C" void kernel_launch(void* const* d_in, const int* in_sizes, int n_in,
                              void* d_out, int out_size, void* d_ws, size_t ws_size,
                              hipStream_t stream) {
    const float4* in4 = (const float4*)d_in[0];
    float4* out = (float4*)d_out;

    dim3 block(OUT_XP, YT_PER_BLOCK, 1);   // 192 threads = 3 waves
    dim3 grid(64 / YT_PER_BLOCK, NZC, 4);  // 32 x 32 x 4 = 4096 blocks
    resize_trilinear_kernel<<<grid, block, 0, stream>>>(in4, out);
}